// Round 1
// baseline (392.343 us; speedup 1.0000x reference)
//
#include <hip/hip_runtime.h>
#include <cmath>

// VAE forward: per-row tiny MLP, memory-bound (112 B/row, ~336 FLOP/row).
// One thread per row; weights (168 floats) staged in LDS; float4 I/O.

__global__ __launch_bounds__(256) void vae_fwd_kernel(
    const float* __restrict__ x,    // [B,8]
    const float* __restrict__ eps,  // [B,4]
    const float* __restrict__ w1,   // [6,8]
    const float* __restrict__ w21,  // [4,6]
    const float* __restrict__ w22,  // [4,6]
    const float* __restrict__ w3,   // [6,4]
    const float* __restrict__ w4,   // [8,6]
    float* __restrict__ out,        // [B*16] = out[B,8] ++ mu[B,4] ++ logvar[B,4]
    int B)
{
    __shared__ float sw[168];
    int t = threadIdx.x;
    // stage all weights: w1[0:48], w21[48:72], w22[72:96], w3[96:120], w4[120:168]
    if (t < 168) {
        float v;
        if      (t < 48)  v = w1[t];
        else if (t < 72)  v = w21[t - 48];
        else if (t < 96)  v = w22[t - 72];
        else if (t < 120) v = w3[t - 96];
        else              v = w4[t - 120];
        sw[t] = v;
    }
    __syncthreads();

    const float* W1  = sw;        // [6][8]
    const float* W21 = sw + 48;   // [4][6]
    const float* W22 = sw + 72;   // [4][6]
    const float* W3  = sw + 96;   // [6][4]
    const float* W4  = sw + 120;  // [8][6]

    int row = blockIdx.x * blockDim.x + t;
    if (row >= B) return;

    // load x row (2x float4) and eps row (1x float4)
    const float4* xv = (const float4*)x;
    float4 x0 = xv[(size_t)row * 2 + 0];
    float4 x1 = xv[(size_t)row * 2 + 1];
    float xi[8] = {x0.x, x0.y, x0.z, x0.w, x1.x, x1.y, x1.z, x1.w};
    float4 e4 = ((const float4*)eps)[row];
    float ei[4] = {e4.x, e4.y, e4.z, e4.w};

    // h1 = elu(x @ w1^T)  [6]
    float h1[6];
#pragma unroll
    for (int j = 0; j < 6; j++) {
        float a = 0.f;
#pragma unroll
        for (int k = 0; k < 8; k++) a += xi[k] * W1[j * 8 + k];
        h1[j] = (a > 0.f) ? a : expm1f(a);
    }

    // mu, logvar, z  [4]
    float mu[4], lv[4], z[4];
#pragma unroll
    for (int j = 0; j < 4; j++) {
        float m = 0.f, l = 0.f;
#pragma unroll
        for (int k = 0; k < 6; k++) {
            m += h1[k] * W21[j * 6 + k];
            l += h1[k] * W22[j * 6 + k];
        }
        mu[j] = m;
        lv[j] = l;
        z[j]  = m + ei[j] * expf(0.5f * l);
    }

    // h3 = elu(z @ w3^T)  [6]
    float h3[6];
#pragma unroll
    for (int j = 0; j < 6; j++) {
        float a = 0.f;
#pragma unroll
        for (int k = 0; k < 4; k++) a += z[k] * W3[j * 4 + k];
        h3[j] = (a > 0.f) ? a : expm1f(a);
    }

    // out = h3 @ w4^T  [8]
    float o[8];
#pragma unroll
    for (int j = 0; j < 8; j++) {
        float a = 0.f;
#pragma unroll
        for (int k = 0; k < 6; k++) a += h3[k] * W4[j * 6 + k];
        o[j] = a;
    }

    // stores (all float4, coalesced within each output region)
    float4* outv = (float4*)out;
    outv[(size_t)row * 2 + 0] = make_float4(o[0], o[1], o[2], o[3]);
    outv[(size_t)row * 2 + 1] = make_float4(o[4], o[5], o[6], o[7]);
    float4* muv = (float4*)(out + (size_t)B * 8);
    muv[row] = make_float4(mu[0], mu[1], mu[2], mu[3]);
    float4* lvv = (float4*)(out + (size_t)B * 12);
    lvv[row] = make_float4(lv[0], lv[1], lv[2], lv[3]);
}

extern "C" void kernel_launch(void* const* d_in, const int* in_sizes, int n_in,
                              void* d_out, int out_size, void* d_ws, size_t ws_size,
                              hipStream_t stream) {
    const float* x   = (const float*)d_in[0];
    const float* eps = (const float*)d_in[1];
    const float* w1  = (const float*)d_in[2];
    const float* w21 = (const float*)d_in[3];
    const float* w22 = (const float*)d_in[4];
    const float* w3  = (const float*)d_in[5];
    const float* w4  = (const float*)d_in[6];
    float* out = (float*)d_out;

    int B = in_sizes[0] / 8;  // x is [B,8]
    int block = 256;
    int grid = (B + block - 1) / block;
    vae_fwd_kernel<<<grid, block, 0, stream>>>(x, eps, w1, w21, w22, w3, w4, out, B);
}

// Round 2
// 388.066 us; speedup vs baseline: 1.0110x; 1.0110x over previous
//
#include <hip/hip_runtime.h>
#include <cmath>

// VAE forward: per-row tiny MLP, memory-bound (112 B/row, ~336 FLOP/row).
// One thread per row. Weights read via wave-uniform scalar loads (s_load ->
// SGPRs, scalar cache) -- no LDS, no __syncthreads. Transcendentals use
// native v_exp_f32 via __expf (absmax threshold 7e-2 gives ample slack).
// Branchless elu: fmax(a,0) + exp(fmin(a,0)) - 1  (exact at a==0).

__device__ __forceinline__ float fast_elu(float a) {
    return fmaxf(a, 0.f) + __expf(fminf(a, 0.f)) - 1.f;
}

__global__ __launch_bounds__(256) void vae_fwd_kernel(
    const float* __restrict__ x,    // [B,8]
    const float* __restrict__ eps,  // [B,4]
    const float* __restrict__ w1,   // [6,8]
    const float* __restrict__ w21,  // [4,6]
    const float* __restrict__ w22,  // [4,6]
    const float* __restrict__ w3,   // [6,4]
    const float* __restrict__ w4,   // [8,6]
    float* __restrict__ out,        // [B*16] = out[B,8] ++ mu[B,4] ++ logvar[B,4]
    int B)
{
    int row = blockIdx.x * blockDim.x + threadIdx.x;
    if (row >= B) return;

    // load x row (2x float4) and eps row (1x float4)
    const float4* xv = (const float4*)x;
    float4 x0 = xv[(size_t)row * 2 + 0];
    float4 x1 = xv[(size_t)row * 2 + 1];
    float xi[8] = {x0.x, x0.y, x0.z, x0.w, x1.x, x1.y, x1.z, x1.w};
    float4 e4 = ((const float4*)eps)[row];
    float ei[4] = {e4.x, e4.y, e4.z, e4.w};

    // h1 = elu(x @ w1^T)  [6]  -- weight reads are wave-uniform -> s_load
    float h1[6];
#pragma unroll
    for (int j = 0; j < 6; j++) {
        float a = 0.f;
#pragma unroll
        for (int k = 0; k < 8; k++) a += xi[k] * w1[j * 8 + k];
        h1[j] = fast_elu(a);
    }

    // mu, logvar, z  [4]
    float mu[4], lv[4], z[4];
#pragma unroll
    for (int j = 0; j < 4; j++) {
        float m = 0.f, l = 0.f;
#pragma unroll
        for (int k = 0; k < 6; k++) {
            m += h1[k] * w21[j * 6 + k];
            l += h1[k] * w22[j * 6 + k];
        }
        mu[j] = m;
        lv[j] = l;
        z[j]  = m + ei[j] * __expf(0.5f * l);
    }

    // h3 = elu(z @ w3^T)  [6]
    float h3[6];
#pragma unroll
    for (int j = 0; j < 6; j++) {
        float a = 0.f;
#pragma unroll
        for (int k = 0; k < 4; k++) a += z[k] * w3[j * 4 + k];
        h3[j] = fast_elu(a);
    }

    // out = h3 @ w4^T  [8]
    float o[8];
#pragma unroll
    for (int j = 0; j < 8; j++) {
        float a = 0.f;
#pragma unroll
        for (int k = 0; k < 6; k++) a += h3[k] * w4[j * 6 + k];
        o[j] = a;
    }

    // stores (all float4, coalesced within each output region)
    float4* outv = (float4*)out;
    outv[(size_t)row * 2 + 0] = make_float4(o[0], o[1], o[2], o[3]);
    outv[(size_t)row * 2 + 1] = make_float4(o[4], o[5], o[6], o[7]);
    float4* muv = (float4*)(out + (size_t)B * 8);
    muv[row] = make_float4(mu[0], mu[1], mu[2], mu[3]);
    float4* lvv = (float4*)(out + (size_t)B * 12);
    lvv[row] = make_float4(lv[0], lv[1], lv[2], lv[3]);
}

extern "C" void kernel_launch(void* const* d_in, const int* in_sizes, int n_in,
                              void* d_out, int out_size, void* d_ws, size_t ws_size,
                              hipStream_t stream) {
    const float* x   = (const float*)d_in[0];
    const float* eps = (const float*)d_in[1];
    const float* w1  = (const float*)d_in[2];
    const float* w21 = (const float*)d_in[3];
    const float* w22 = (const float*)d_in[4];
    const float* w3  = (const float*)d_in[5];
    const float* w4  = (const float*)d_in[6];
    float* out = (float*)d_out;

    int B = in_sizes[0] / 8;  // x is [B,8]
    int block = 256;
    int grid = (B + block - 1) / block;
    vae_fwd_kernel<<<grid, block, 0, stream>>>(x, eps, w1, w21, w22, w3, w4, out, B);
}